// Round 1
// baseline (38.110 us; speedup 1.0000x reference)
//
#include <hip/hip_runtime.h>

// eTofts model:
//   B=8, T=60, H=W=256.  params[B,3,H,W], Cp[B,T], S0[B,1,H,W], T1[B,1,H,W]
//   out St[B,T,H,W] fp32.
// Memory-bound: 125.8 MB out + 10.5 MB in ~= 22 us floor at 6.3 TB/s.

#define N_TIME 60
#define HW (256 * 256)
#define PIX_PER_THREAD 4

__global__ __launch_bounds__(256) void etofts_kernel(
    const float* __restrict__ params,  // [B,3,H,W]
    const float* __restrict__ Cp,      // [B,T]
    const float* __restrict__ S0,      // [B,1,H,W]
    const float* __restrict__ T1,      // [B,1,H,W]
    float* __restrict__ out)           // [B,T,H,W]
{
    const float DT      = 5.0f;          // DELTT
    const float TR      = 5.0f;
    const float EPS     = 1e-8f;
    const float COS_FA  = 0.9848077530122081f;   // cos(10 deg)
    const float QCOEF   = 4.5f * 5.0f / 1000.0f; // R1*TR/1000 = 0.0225

    const int gid  = blockIdx.x * blockDim.x + threadIdx.x;   // one per 4 pixels
    const int b    = gid / (HW / PIX_PER_THREAD);             // block-uniform
    const int pix  = (gid % (HW / PIX_PER_THREAD)) * PIX_PER_THREAD;

    const size_t plane = (size_t)b * HW + pix;

    const float4 kt4 = *reinterpret_cast<const float4*>(params + ((size_t)b * 3 + 0) * HW + pix);
    const float4 vp4 = *reinterpret_cast<const float4*>(params + ((size_t)b * 3 + 1) * HW + pix);
    const float4 ve4 = *reinterpret_cast<const float4*>(params + ((size_t)b * 3 + 2) * HW + pix);
    const float4 s04 = *reinterpret_cast<const float4*>(S0 + plane);
    const float4 t14 = *reinterpret_cast<const float4*>(T1 + plane);

    float Kt[PIX_PER_THREAD], vp[PIX_PER_THREAD], decay[PIX_PER_THREAD];
    float Ce[PIX_PER_THREAD], eP[PIX_PER_THREAD], Kc[PIX_PER_THREAD], den1[PIX_PER_THREAD];

    {
        const float ktv[4] = {kt4.x, kt4.y, kt4.z, kt4.w};
        const float vpv[4] = {vp4.x, vp4.y, vp4.z, vp4.w};
        const float vev[4] = {ve4.x, ve4.y, ve4.z, ve4.w};
        const float s0v[4] = {s04.x, s04.y, s04.z, s04.w};
        const float t1v[4] = {t14.x, t14.y, t14.z, t14.w};
#pragma unroll
        for (int i = 0; i < PIX_PER_THREAD; ++i) {
            const float Ktrans = ktv[i] * (1.0f / 60.0f);
            const float Kep    = __fdividef(Ktrans, vev[i] + EPS);
            Kt[i]    = Ktrans;
            vp[i]    = vpv[i];
            decay[i] = __expf(-Kep * DT);
            const float P = __fdividef(TR, t1v[i] + EPS);
            const float e = __expf(-P);
            eP[i]   = e;
            Kc[i]   = (1.0f - COS_FA * e) * s0v[i];  // (1 - cos*eP) * S0
            den1[i] = 1.0f - e;                      // (1 - eP)
            Ce[i]   = 0.0f;
        }
    }

    const float* cp_row = Cp + b * N_TIME;
    float* outp = out + (size_t)b * N_TIME * HW + pix;

    for (int t = 0; t < N_TIME; ++t) {
        const float cp   = cp_row[t];      // scalar (wave-uniform) load
        const float cpdt = cp * DT;
        float st[PIX_PER_THREAD];
#pragma unroll
        for (int i = 0; i < PIX_PER_THREAD; ++i) {
            Ce[i] = Ce[i] * decay[i] + cpdt;                 // linear recurrence
            const float Ct  = vp[i] * cp + Kt[i] * Ce[i];
            const float ePQ = eP[i] * __expf(-QCOEF * Ct);   // exp(-P-Q)
            const float num = (1.0f - ePQ) * Kc[i];
            const float den = (1.0f - COS_FA * ePQ) * den1[i] + EPS;
            st[i] = __fdividef(num, den);
        }
        float4 v = make_float4(st[0], st[1], st[2], st[3]);
        *reinterpret_cast<float4*>(outp + (size_t)t * HW) = v;
    }
}

extern "C" void kernel_launch(void* const* d_in, const int* in_sizes, int n_in,
                              void* d_out, int out_size, void* d_ws, size_t ws_size,
                              hipStream_t stream) {
    const float* params = (const float*)d_in[0];
    const float* Cp     = (const float*)d_in[1];
    const float* S0     = (const float*)d_in[2];
    const float* T1     = (const float*)d_in[3];
    float* out          = (float*)d_out;

    const int B = 8;
    const int total_threads = B * HW / PIX_PER_THREAD;  // 131072
    const int block = 256;
    const int grid = total_threads / block;             // 512
    etofts_kernel<<<grid, block, 0, stream>>>(params, Cp, S0, T1, out);
}

// Round 2
// 37.098 us; speedup vs baseline: 1.0273x; 1.0273x over previous
//
#include <hip/hip_runtime.h>

// eTofts model: B=8, T=60, H=W=256.
//   params[B,3,H,W], Cp[B,T], S0[B,1,H,W], T1[B,1,H,W] -> St[B,T,H,W] fp32
// Memory-bound: 125.8 MB out + 10.5 MB in => ~20 us floor at ~6.5-7 TB/s.
//
// R1 lesson: 38 us came from (a) Cp as a vector load on the recurrence
// critical path, (b) only 512 blocks (8 waves/CU). Fix: block-uniform b so
// Cp becomes scalar s_load; split T into 4 chunks of 15 per thread (prologue
// replays the fma-only recurrence, <=45 fmas) -> 2048 blocks.

#define N_TIME 60
#define HW (256 * 256)
#define PIX_PER_THREAD 4
#define CHUNKS 4
#define CHUNK_LEN (N_TIME / CHUNKS)              // 15
#define BLOCKS_PER_CHUNK (HW / (PIX_PER_THREAD * 256))  // 64

__global__ __launch_bounds__(256) void etofts_kernel(
    const float* __restrict__ params,  // [B,3,H,W]
    const float* __restrict__ Cp,      // [B,T]
    const float* __restrict__ S0,      // [B,1,H,W]
    const float* __restrict__ T1,      // [B,1,H,W]
    float* __restrict__ out)           // [B,T,H,W]
{
    const float DT     = 5.0f;
    const float TR     = 5.0f;
    const float EPS    = 1e-8f;
    const float COS_FA = 0.9848077530122081f;            // cos(10 deg)
    const float QC2    = 0.0225f * 1.4426950408889634f;  // (R1*TR/1000)*log2(e)

    // b and chunk derived ONLY from blockIdx.x -> wave-uniform -> Cp loads
    // compile to scalar s_load.
    const int bx    = blockIdx.x;
    const int b     = bx >> 8;            // 256 blocks per batch
    const int chunk = (bx >> 6) & 3;
    const int blk   = bx & 63;
    const int pix   = (blk * 256 + threadIdx.x) * PIX_PER_THREAD;

    const size_t plane = (size_t)b * HW + pix;

    const float4 kt4 = *reinterpret_cast<const float4*>(params + ((size_t)b * 3 + 0) * HW + pix);
    const float4 vp4 = *reinterpret_cast<const float4*>(params + ((size_t)b * 3 + 1) * HW + pix);
    const float4 ve4 = *reinterpret_cast<const float4*>(params + ((size_t)b * 3 + 2) * HW + pix);
    const float4 s04 = *reinterpret_cast<const float4*>(S0 + plane);
    const float4 t14 = *reinterpret_cast<const float4*>(T1 + plane);

    float Kt[4], vp[4], decay[4], Ce[4], eP[4], Kc[4], d0[4], d1[4];
    {
        const float ktv[4] = {kt4.x, kt4.y, kt4.z, kt4.w};
        const float vpv[4] = {vp4.x, vp4.y, vp4.z, vp4.w};
        const float vev[4] = {ve4.x, ve4.y, ve4.z, ve4.w};
        const float s0v[4] = {s04.x, s04.y, s04.z, s04.w};
        const float t1v[4] = {t14.x, t14.y, t14.z, t14.w};
#pragma unroll
        for (int i = 0; i < 4; ++i) {
            const float Ktrans = ktv[i] * (1.0f / 60.0f);
            const float Kep    = __fdividef(Ktrans, vev[i] + EPS);
            Kt[i]    = Ktrans;
            vp[i]    = vpv[i];
            decay[i] = __expf(-Kep * DT);
            const float P = __fdividef(TR, t1v[i] + EPS);
            const float e = __expf(-P);
            eP[i] = e;
            Kc[i] = (1.0f - COS_FA * e) * s0v[i];   // numerator factor * S0
            const float den1 = 1.0f - e;
            d0[i] = den1 + EPS;                      // den = d0 - d1*ePQ
            d1[i] = COS_FA * den1;
            Ce[i] = 0.0f;
        }
    }

    const float* cp_row = Cp + b * N_TIME;   // uniform base -> s_load
    const int t0 = chunk * CHUNK_LEN;

    // Prologue: replay recurrence (fma only) up to this chunk's start.
    for (int t = 0; t < t0; ++t) {
        const float cpdt = cp_row[t] * DT;
#pragma unroll
        for (int i = 0; i < 4; ++i) Ce[i] = Ce[i] * decay[i] + cpdt;
    }

    float* outp = out + (size_t)b * N_TIME * HW + (size_t)t0 * HW + pix;

#pragma unroll
    for (int k = 0; k < CHUNK_LEN; ++k) {
        const float cp   = cp_row[t0 + k];
        const float cpdt = cp * DT;
        float st[4];
#pragma unroll
        for (int i = 0; i < 4; ++i) {
            Ce[i] = Ce[i] * decay[i] + cpdt;
            const float Ct  = vp[i] * cp + Kt[i] * Ce[i];
            const float ePQ = eP[i] * exp2f(-QC2 * Ct);       // exp(-P-Q)
            const float num = Kc[i] - Kc[i] * ePQ;            // (1-ePQ)*Kc
            const float den = d0[i] - d1[i] * ePQ;            // (1-cos*ePQ)*(1-eP)+EPS
            st[i] = __fdividef(num, den);
        }
        *reinterpret_cast<float4*>(outp + (size_t)k * HW) =
            make_float4(st[0], st[1], st[2], st[3]);
    }
}

extern "C" void kernel_launch(void* const* d_in, const int* in_sizes, int n_in,
                              void* d_out, int out_size, void* d_ws, size_t ws_size,
                              hipStream_t stream) {
    const float* params = (const float*)d_in[0];
    const float* Cp     = (const float*)d_in[1];
    const float* S0     = (const float*)d_in[2];
    const float* T1     = (const float*)d_in[3];
    float* out          = (float*)d_out;

    const int grid = 8 * CHUNKS * BLOCKS_PER_CHUNK;  // 2048 blocks
    etofts_kernel<<<grid, 256, 0, stream>>>(params, Cp, S0, T1, out);
}

// Round 3
// 33.768 us; speedup vs baseline: 1.1286x; 1.0986x over previous
//
#include <hip/hip_runtime.h>

// eTofts model: B=8, T=60, H=W=256.
//   params[B,3,H,W], Cp[B,T], S0[B,1,H,W], T1[B,1,H,W] -> St[B,T,H,W] fp32
// Memory-bound: 125.8 MB out + 10.5 MB in => ~20 us floor at ~7 TB/s.
//
// R2 lesson: 38->37 us despite 4x occupancy => bandwidth wall. 262 MB (out
// write + out RFO-read + in) / 37.1 us = 7.05 TB/s exactly -> output stores
// are fetching lines before writing. Fix: nontemporal (nt) stores, no-allocate.

#define N_TIME 60
#define HW (256 * 256)
#define PIX_PER_THREAD 4
#define CHUNKS 4
#define CHUNK_LEN (N_TIME / CHUNKS)                     // 15
#define BLOCKS_PER_CHUNK (HW / (PIX_PER_THREAD * 256))  // 64

typedef float f32x4 __attribute__((ext_vector_type(4)));

__global__ __launch_bounds__(256) void etofts_kernel(
    const float* __restrict__ params,  // [B,3,H,W]
    const float* __restrict__ Cp,      // [B,T]
    const float* __restrict__ S0,      // [B,1,H,W]
    const float* __restrict__ T1,      // [B,1,H,W]
    float* __restrict__ out)           // [B,T,H,W]
{
    const float DT     = 5.0f;
    const float TR     = 5.0f;
    const float EPS    = 1e-8f;
    const float COS_FA = 0.9848077530122081f;            // cos(10 deg)
    const float QC2    = 0.0225f * 1.4426950408889634f;  // (R1*TR/1000)*log2(e)

    // b and chunk derived ONLY from blockIdx.x -> wave-uniform -> Cp loads
    // compile to scalar s_load.
    const int bx    = blockIdx.x;
    const int b     = bx >> 8;            // 256 blocks per batch
    const int chunk = (bx >> 6) & 3;
    const int blk   = bx & 63;
    const int pix   = (blk * 256 + threadIdx.x) * PIX_PER_THREAD;

    const size_t plane = (size_t)b * HW + pix;

    const float4 kt4 = *reinterpret_cast<const float4*>(params + ((size_t)b * 3 + 0) * HW + pix);
    const float4 vp4 = *reinterpret_cast<const float4*>(params + ((size_t)b * 3 + 1) * HW + pix);
    const float4 ve4 = *reinterpret_cast<const float4*>(params + ((size_t)b * 3 + 2) * HW + pix);
    const float4 s04 = *reinterpret_cast<const float4*>(S0 + plane);
    const float4 t14 = *reinterpret_cast<const float4*>(T1 + plane);

    float Kt[4], vp[4], decay[4], Ce[4], eP[4], Kc[4], d0[4], d1[4];
    {
        const float ktv[4] = {kt4.x, kt4.y, kt4.z, kt4.w};
        const float vpv[4] = {vp4.x, vp4.y, vp4.z, vp4.w};
        const float vev[4] = {ve4.x, ve4.y, ve4.z, ve4.w};
        const float s0v[4] = {s04.x, s04.y, s04.z, s04.w};
        const float t1v[4] = {t14.x, t14.y, t14.z, t14.w};
#pragma unroll
        for (int i = 0; i < 4; ++i) {
            const float Ktrans = ktv[i] * (1.0f / 60.0f);
            const float Kep    = __fdividef(Ktrans, vev[i] + EPS);
            Kt[i]    = Ktrans;
            vp[i]    = vpv[i];
            decay[i] = __expf(-Kep * DT);
            const float P = __fdividef(TR, t1v[i] + EPS);
            const float e = __expf(-P);
            eP[i] = e;
            Kc[i] = (1.0f - COS_FA * e) * s0v[i];   // numerator factor * S0
            const float den1 = 1.0f - e;
            d0[i] = den1 + EPS;                      // den = d0 - d1*ePQ
            d1[i] = COS_FA * den1;
            Ce[i] = 0.0f;
        }
    }

    const float* cp_row = Cp + b * N_TIME;   // uniform base -> s_load
    const int t0 = chunk * CHUNK_LEN;

    // Prologue: replay recurrence (fma only) up to this chunk's start.
    for (int t = 0; t < t0; ++t) {
        const float cpdt = cp_row[t] * DT;
#pragma unroll
        for (int i = 0; i < 4; ++i) Ce[i] = Ce[i] * decay[i] + cpdt;
    }

    float* outp = out + (size_t)b * N_TIME * HW + (size_t)t0 * HW + pix;

#pragma unroll
    for (int k = 0; k < CHUNK_LEN; ++k) {
        const float cp   = cp_row[t0 + k];
        const float cpdt = cp * DT;
        float st[4];
#pragma unroll
        for (int i = 0; i < 4; ++i) {
            Ce[i] = Ce[i] * decay[i] + cpdt;
            const float Ct  = vp[i] * cp + Kt[i] * Ce[i];
            const float ePQ = eP[i] * exp2f(-QC2 * Ct);       // exp(-P-Q)
            const float num = Kc[i] - Kc[i] * ePQ;            // (1-ePQ)*Kc
            const float den = d0[i] - d1[i] * ePQ;            // (1-cos*ePQ)*(1-eP)+EPS
            st[i] = __fdividef(num, den);
        }
        f32x4 v = {st[0], st[1], st[2], st[3]};
        // Nontemporal: no-allocate streaming store, avoids fetch-on-write.
        __builtin_nontemporal_store(v, reinterpret_cast<f32x4*>(outp + (size_t)k * HW));
    }
}

extern "C" void kernel_launch(void* const* d_in, const int* in_sizes, int n_in,
                              void* d_out, int out_size, void* d_ws, size_t ws_size,
                              hipStream_t stream) {
    const float* params = (const float*)d_in[0];
    const float* Cp     = (const float*)d_in[1];
    const float* S0     = (const float*)d_in[2];
    const float* T1     = (const float*)d_in[3];
    float* out          = (float*)d_out;

    const int grid = 8 * CHUNKS * BLOCKS_PER_CHUNK;  // 2048 blocks
    etofts_kernel<<<grid, 256, 0, stream>>>(params, Cp, S0, T1, out);
}

// Round 4
// 33.108 us; speedup vs baseline: 1.1511x; 1.0199x over previous
//
#include <hip/hip_runtime.h>

// eTofts model: B=8, T=60, H=W=256.
//   params[B,3,H,W], Cp[B,T], S0[B,1,H,W], T1[B,1,H,W] -> St[B,T,H,W] fp32
// True traffic: 125.8 MB out + ~10.5 MB in => ~20 us floor at ~7 TB/s.
//
// R3 lesson: nt stores only -9%. R1/R2/R3 all ~34-38 us (~4 TB/s) across very
// different occupancies => not latency, not raw BW, not RFO. Remaining theory:
// write-stream granularity. Waves emitted 1 KB then jumped 256 KB (next
// T-plane); ~8K concurrent 1KB streams thrash DRAM rows. Fill kernel (7 TB/s)
// writes long contiguous runs. Fix: 16 px/thread as 4 coalesced segments ->
// each wave writes a 4 KB CONTIGUOUS run per frame (4 back-to-back 1KB
// store instrs), 4x longer runs, 4x fewer streams.

#define N_TIME 60
#define HW (256 * 256)
#define CHUNKS 4
#define CHUNK_LEN (N_TIME / CHUNKS)   // 15
#define PXB 4096                      // pixels per block (256 thr * 16 px)

typedef float f32x4 __attribute__((ext_vector_type(4)));

__global__ __launch_bounds__(256, 2) void etofts_kernel(
    const float* __restrict__ params,  // [B,3,H,W]
    const float* __restrict__ Cp,      // [B,T]
    const float* __restrict__ S0,      // [B,1,H,W]
    const float* __restrict__ T1,      // [B,1,H,W]
    float* __restrict__ out)           // [B,T,H,W]
{
    const float DT     = 5.0f;
    const float TR     = 5.0f;
    const float EPS    = 1e-8f;
    const float COS_FA = 0.9848077530122081f;            // cos(10 deg)
    const float QC2    = 0.0225f * 1.4426950408889634f;  // (R1*TR/1000)*log2(e)

    // 512 blocks: b = bx>>6 (64/batch), chunk = (bx>>4)&3, blk = bx&15.
    const int bx    = blockIdx.x;
    const int b     = bx >> 6;
    const int chunk = (bx >> 4) & 3;
    const int blk   = bx & 15;

    // Wave w owns a 4 KB contiguous span per frame: px = blk*4096 + w*1024
    //  + q*256 + lane*4, q = 0..3.  Store instr (fixed q) = 1 KB contiguous.
    const int w    = threadIdx.x >> 6;
    const int lane = threadIdx.x & 63;
    const int pixw = blk * PXB + w * 1024 + lane * 4;

    const float* p0 = params + ((size_t)b * 3 + 0) * HW + pixw;
    const float* p1 = params + ((size_t)b * 3 + 1) * HW + pixw;
    const float* p2 = params + ((size_t)b * 3 + 2) * HW + pixw;
    const float* ps = S0 + (size_t)b * HW + pixw;
    const float* pt = T1 + (size_t)b * HW + pixw;

    float Kt[16], vp[16], decay[16], Ce[16], eP[16], Kc[16], d0[16], d1[16];

#pragma unroll
    for (int q = 0; q < 4; ++q) {
        const float4 kt4 = *reinterpret_cast<const float4*>(p0 + q * 256);
        const float4 vp4 = *reinterpret_cast<const float4*>(p1 + q * 256);
        const float4 ve4 = *reinterpret_cast<const float4*>(p2 + q * 256);
        const float4 s04 = *reinterpret_cast<const float4*>(ps + q * 256);
        const float4 t14 = *reinterpret_cast<const float4*>(pt + q * 256);
        const float ktv[4] = {kt4.x, kt4.y, kt4.z, kt4.w};
        const float vpv[4] = {vp4.x, vp4.y, vp4.z, vp4.w};
        const float vev[4] = {ve4.x, ve4.y, ve4.z, ve4.w};
        const float s0v[4] = {s04.x, s04.y, s04.z, s04.w};
        const float t1v[4] = {t14.x, t14.y, t14.z, t14.w};
#pragma unroll
        for (int i = 0; i < 4; ++i) {
            const int j = q * 4 + i;
            const float Ktrans = ktv[i] * (1.0f / 60.0f);
            const float Kep    = __fdividef(Ktrans, vev[i] + EPS);
            Kt[j]    = Ktrans;
            vp[j]    = vpv[i];
            decay[j] = __expf(-Kep * DT);
            const float P = __fdividef(TR, t1v[i] + EPS);
            const float e = __expf(-P);
            eP[j] = e;
            Kc[j] = (1.0f - COS_FA * e) * s0v[i];
            const float den1 = 1.0f - e;
            d0[j] = den1 + EPS;              // den = d0 - d1*ePQ
            d1[j] = COS_FA * den1;
            Ce[j] = 0.0f;
        }
    }

    const float* cp_row = Cp + b * N_TIME;   // uniform -> s_load
    const int t0 = chunk * CHUNK_LEN;

    // Replay the fma-only recurrence up to this chunk's start (<=45 iters).
    for (int t = 0; t < t0; ++t) {
        const float cpdt = cp_row[t] * DT;
#pragma unroll
        for (int j = 0; j < 16; ++j) Ce[j] = Ce[j] * decay[j] + cpdt;
    }

    float* outp = out + ((size_t)(b * N_TIME + t0)) * HW + pixw;

#pragma unroll
    for (int k = 0; k < CHUNK_LEN; ++k) {
        const float cp   = cp_row[t0 + k];
        const float cpdt = cp * DT;
        float* op = outp + (size_t)k * HW;
#pragma unroll
        for (int q = 0; q < 4; ++q) {
            float st[4];
#pragma unroll
            for (int i = 0; i < 4; ++i) {
                const int j = q * 4 + i;
                Ce[j] = Ce[j] * decay[j] + cpdt;
                const float Ct  = vp[j] * cp + Kt[j] * Ce[j];
                const float ePQ = eP[j] * exp2f(-QC2 * Ct);
                const float num = Kc[j] - Kc[j] * ePQ;
                const float den = d0[j] - d1[j] * ePQ;
                st[i] = __fdividef(num, den);
            }
            f32x4 v = {st[0], st[1], st[2], st[3]};
            __builtin_nontemporal_store(v, reinterpret_cast<f32x4*>(op + q * 256));
        }
    }
}

extern "C" void kernel_launch(void* const* d_in, const int* in_sizes, int n_in,
                              void* d_out, int out_size, void* d_ws, size_t ws_size,
                              hipStream_t stream) {
    const float* params = (const float*)d_in[0];
    const float* Cp     = (const float*)d_in[1];
    const float* S0     = (const float*)d_in[2];
    const float* T1     = (const float*)d_in[3];
    float* out          = (float*)d_out;

    const int grid = 8 * CHUNKS * (HW / PXB);  // 512 blocks
    etofts_kernel<<<grid, 256, 0, stream>>>(params, Cp, S0, T1, out);
}